// Round 4
// baseline (267.148 us; speedup 1.0000x reference)
//
#include <hip/hip_runtime.h>
#include <hip/hip_bf16.h>

#define NN 4096
#define FF 512
#define NH 8
#define DH 64

typedef __attribute__((ext_vector_type(8))) short bf16x8;
typedef __attribute__((ext_vector_type(4))) float f32x4;

// ws layout in ushort elements:
//  X_BF  [4096][512]                    @ 0
//  W_BF  [3][512][512]                  @ 2097152
//  QF    [8][256 blk][2 half][64 ln][8] @ 2883584   (MFMA A-fragment order)
//  KF    [8][256 blk][2 half][64 ln][8] @ 4980736   (MFMA B-fragment order)
//  VF    [8][64 kb][4 dt][2 hf][64][8]  @ 7077888   (MFMA B-fragment order, d-major)
//  PACC  bf16 [4 ks][8 h][4096][64]     @ 9175040   (8388608 ushorts)
//  PDEN  f32  [4 ks][8 h][4096]         @ ushort 17563648 (byte 35127296)
#define X_OFF  0
#define W_OFF  2097152
#define QF_OFF 2883584
#define KF_OFF 4980736
#define VF_OFF 7077888
#define PACC_OFF 9175040
#define PDEN_USHORT_OFF 17563648

__device__ __forceinline__ ushort f2bf(float f) {
    __hip_bfloat16 h = __float2bfloat16(f);
    return __builtin_bit_cast(ushort, h);
}
__device__ __forceinline__ float bf2f(ushort u) {
    unsigned int v = ((unsigned int)u) << 16;
    return __builtin_bit_cast(float, v);
}

// ---------------- kernel 0: f32 -> bf16 convert (x, Wq, Wk, Wv) ----------------
__global__ __launch_bounds__(256) void cvt_kernel(const float* __restrict__ x,
                                                  const float* __restrict__ wq,
                                                  const float* __restrict__ wk,
                                                  const float* __restrict__ wv,
                                                  ushort* __restrict__ ws) {
    int i = blockIdx.x * 256 + threadIdx.x;
    int base = i * 4;
    const float* src;
    int off;
    if (base < 2097152) { src = x; off = base; }
    else {
        int t = base - 2097152;
        int m = t >> 18;
        src = (m == 0) ? wq : ((m == 1) ? wk : wv);
        off = t & 262143;
    }
    float4 v = *reinterpret_cast<const float4*>(src + off);
    ushort4 o;
    o.x = f2bf(v.x); o.y = f2bf(v.y); o.z = f2bf(v.z); o.w = f2bf(v.w);
    *reinterpret_cast<ushort4*>(ws + base) = o;
}

// ---------------- kernel 1: QKV projection, outputs in MFMA-fragment order ----------------
__global__ __launch_bounds__(256) void qkv_kernel(ushort* __restrict__ ws) {
    int bx = blockIdx.x;
    int mat = bx >> 3;          // 0=Q,1=K,2=V
    int fb  = bx & 7;           // head
    int mb  = blockIdx.y;
    int wave = threadIdx.x >> 6, lane = threadIdx.x & 63;
    int la = lane & 15, lk = lane >> 4;

    int m_base = mb * 64 + wave * 16;
    int f_base = fb * 64;

    const ushort* xb = ws + X_OFF;
    const ushort* wb = ws + W_OFF + mat * 262144;

    f32x4 acc[4];
#pragma unroll
    for (int t = 0; t < 4; ++t) acc[t] = (f32x4){0.f, 0.f, 0.f, 0.f};

#pragma unroll 4
    for (int k0 = 0; k0 < 512; k0 += 32) {
        bf16x8 a = *reinterpret_cast<const bf16x8*>(xb + (size_t)(m_base + la) * 512 + k0 + lk * 8);
#pragma unroll
        for (int ft = 0; ft < 4; ++ft) {
            bf16x8 b = *reinterpret_cast<const bf16x8*>(wb + (size_t)(f_base + ft * 16 + la) * 512 + k0 + lk * 8);
            acc[ft] = __builtin_amdgcn_mfma_f32_16x16x32_bf16(a, b, acc[ft], 0, 0, 0);
        }
    }

#pragma unroll
    for (int ft = 0; ft < 4; ++ft) {
#pragma unroll
        for (int r = 0; r < 4; ++r) {
            int n = m_base + lk * 4 + r;
            int d = ft * 16 + la;          // head-local feature
            ushort v = f2bf(acc[ft][r]);
            if (mat < 2) {
                // Q/K fragment order: [blk=n>>4][half=d>>5][lk=(d>>3)&3][rr=n&15][e=d&7]
                ushort* base = ws + (mat == 0 ? QF_OFF : KF_OFF) + (size_t)fb * 262144;
                int blk = n >> 4, rr = n & 15;
                int half = d >> 5, lkk = (d >> 3) & 3, e = d & 7;
                base[(((size_t)blk * 2 + half) * 64 + lkk * 16 + rr) * 8 + e] = v;
            } else {
                // V fragment order: [kb64=n>>6][dt=d>>4][hf][lkv][lav=d&15][ev]
                ushort* base = ws + VF_OFF + (size_t)fb * 262144;
                int kb64 = n >> 6, kc = n & 63;
                int hf = kc >> 5, lkv = (kc >> 3) & 3, ev = kc & 7;
                int dt = d >> 4, lav = d & 15;
                base[((((size_t)kb64 * 4 + dt) * 2 + hf) * 64 + lkv * 16 + lav) * 8 + ev] = v;
            }
        }
    }
}

// ---------------- kernel 2: masked attention, k-split, bf16 partials ----------------
// grid 1024: h = bid&7 (XCD-pinned), qb = (bid>>3)&31, ks = bid>>8. 4 waves x 32 q-rows.
__global__ __launch_bounds__(256, 4) void attn_kernel(const int* __restrict__ adj,
                                                      const ushort* __restrict__ ws,
                                                      ushort* __restrict__ pacc,
                                                      float* __restrict__ pden) {
    __shared__ ushort P[4][32][72];   // per-wave private

    int bid = blockIdx.x;
    int h = bid & 7, qb = (bid >> 3) & 31, ks = bid >> 8;
    int wave = threadIdx.x >> 6, lane = threadIdx.x & 63;
    int la = lane & 15, lk = lane >> 4;
    int q0 = qb * 128 + wave * 32;

    const ushort* Qh = ws + QF_OFF + (size_t)h * 262144;
    const ushort* Kh = ws + KF_OFF + (size_t)h * 262144;
    const ushort* Vh = ws + VF_OFF + (size_t)h * 262144;
    const int* adjh = adj + (size_t)h * 16777216;

    bf16x8 qa[2][2];
#pragma unroll
    for (int qs = 0; qs < 2; ++qs)
#pragma unroll
        for (int hf = 0; hf < 2; ++hf)
            qa[qs][hf] = *reinterpret_cast<const bf16x8*>(
                Qh + ((((size_t)((q0 >> 4) + qs)) * 2 + hf) * 64 + lane) * 8);

    f32x4 acc[2][4];
    float den[2][4];
    int rowoff[2][4];
#pragma unroll
    for (int qs = 0; qs < 2; ++qs)
#pragma unroll
        for (int r = 0; r < 4; ++r) {
            acc[qs][r] = (f32x4){0.f, 0.f, 0.f, 0.f};
            den[qs][r] = 0.f;
            rowoff[qs][r] = (q0 + qs * 16 + lk * 4 + r) * 4096 + la;
        }

    const float scale = 0.044194173824159216f;   // 1/sqrt(512)
    const f32x4 zero = {0.f, 0.f, 0.f, 0.f};

    for (int kb16 = ks * 64; kb16 < ks * 64 + 64; kb16 += 4) {
        int kb64 = kb16 >> 2;
        bf16x8 vb[4][2];
#pragma unroll
        for (int dt = 0; dt < 4; ++dt)
#pragma unroll
            for (int hf = 0; hf < 2; ++hf)
                vb[dt][hf] = *reinterpret_cast<const bf16x8*>(
                    Vh + ((((size_t)kb64 * 4 + dt) * 2 + hf) * 64 + lane) * 8);

#pragma unroll
        for (int kt = 0; kt < 4; ++kt) {
            const ushort* kp = Kh + (((size_t)(kb16 + kt) * 2) * 64 + lane) * 8;
            bf16x8 kf0 = *reinterpret_cast<const bf16x8*>(kp);
            bf16x8 kf1 = *reinterpret_cast<const bf16x8*>(kp + 512);
            int colb = (kb16 + kt) * 16;
#pragma unroll
            for (int qs = 0; qs < 2; ++qs) {
                f32x4 s = __builtin_amdgcn_mfma_f32_16x16x32_bf16(qa[qs][0], kf0, zero, 0, 0, 0);
                s = __builtin_amdgcn_mfma_f32_16x16x32_bf16(qa[qs][1], kf1, s, 0, 0, 0);
#pragma unroll
                for (int r = 0; r < 4; ++r) {
                    int m = __builtin_nontemporal_load(adjh + rowoff[qs][r] + colb);
                    float p = m ? __expf(s[r] * scale) : 0.f;
                    den[qs][r] += p;
                    P[wave][qs * 16 + lk * 4 + r][kt * 16 + la] = f2bf(p);
                }
            }
        }
        // PV: same-wave LDS write->read (lgkmcnt ordered, no barrier)
#pragma unroll
        for (int qs = 0; qs < 2; ++qs) {
            bf16x8 pa0 = *reinterpret_cast<const bf16x8*>(&P[wave][qs * 16 + la][lk * 8]);
            bf16x8 pa1 = *reinterpret_cast<const bf16x8*>(&P[wave][qs * 16 + la][32 + lk * 8]);
#pragma unroll
            for (int dt = 0; dt < 4; ++dt) {
                acc[qs][dt] = __builtin_amdgcn_mfma_f32_16x16x32_bf16(pa0, vb[dt][0], acc[qs][dt], 0, 0, 0);
                acc[qs][dt] = __builtin_amdgcn_mfma_f32_16x16x32_bf16(pa1, vb[dt][1], acc[qs][dt], 0, 0, 0);
            }
        }
    }

    // reduce den over the 16-lane key dimension
#pragma unroll
    for (int qs = 0; qs < 2; ++qs)
#pragma unroll
        for (int r = 0; r < 4; ++r)
#pragma unroll
            for (int m = 1; m < 16; m <<= 1)
                den[qs][r] += __shfl_xor(den[qs][r], m, 64);

    // store bf16 partial acc + f32 partial den
    ushort* pa_out = pacc + ((size_t)ks * 8 + h) * 4096 * 64;
#pragma unroll
    for (int qs = 0; qs < 2; ++qs)
#pragma unroll
        for (int dt = 0; dt < 4; ++dt)
#pragma unroll
            for (int r = 0; r < 4; ++r) {
                int q = q0 + qs * 16 + lk * 4 + r;
                __builtin_nontemporal_store(f2bf(acc[qs][dt][r]), pa_out + (size_t)q * 64 + dt * 16 + la);
            }
    if (la == 0) {
        float* pd = pden + ((size_t)ks * 8 + h) * 4096;
#pragma unroll
        for (int qs = 0; qs < 2; ++qs)
#pragma unroll
            for (int r = 0; r < 4; ++r)
                pd[q0 + qs * 16 + lk * 4 + r] = den[qs][r];
    }
}

// ---------------- kernel 3: combine bf16 partials + epilogue ----------------
__global__ __launch_bounds__(256) void combine_kernel(const float* __restrict__ x,
                                                      const ushort* __restrict__ pacc,
                                                      const float* __restrict__ pden,
                                                      float* __restrict__ out) {
    int idx = blockIdx.x * 256 + threadIdx.x;   // 524288 total
    int n = idx >> 7, fq = idx & 127;
    int h = fq >> 4;
    int d4 = (fq & 15) * 4;

    float4 o = make_float4(0.f, 0.f, 0.f, 0.f);
    float den = 0.f;
#pragma unroll
    for (int ksp = 0; ksp < 4; ++ksp) {
        const ushort* pa = pacc + (((size_t)ksp * 8 + h) * 4096 + n) * 64 + h * 0 + d4;
        ushort4 p = *reinterpret_cast<const ushort4*>(pa);
        o.x += bf2f(p.x); o.y += bf2f(p.y); o.z += bf2f(p.z); o.w += bf2f(p.w);
        den += pden[((size_t)ksp * 8 + h) * 4096 + n];
    }
    float4 xv = *reinterpret_cast<const float4*>(x + (size_t)n * 512 + fq * 4);
    float inv = 1.f / den;
    float4 r;
    r.x = o.x * inv + xv.x;
    r.y = o.y * inv + xv.y;
    r.z = o.z * inv + xv.z;
    r.w = o.w * inv + xv.w;
    r.x = (r.x > 0.f) ? r.x : (__expf(r.x) - 1.f);
    r.y = (r.y > 0.f) ? r.y : (__expf(r.y) - 1.f);
    r.z = (r.z > 0.f) ? r.z : (__expf(r.z) - 1.f);
    r.w = (r.w > 0.f) ? r.w : (__expf(r.w) - 1.f);
    *reinterpret_cast<float4*>(out + (size_t)n * 512 + fq * 4) = r;
}

extern "C" void kernel_launch(void* const* d_in, const int* in_sizes, int n_in,
                              void* d_out, int out_size, void* d_ws, size_t ws_size,
                              hipStream_t stream) {
    const float* x  = (const float*)d_in[0];
    const float* wq = (const float*)d_in[1];
    const float* wk = (const float*)d_in[2];
    const float* wv = (const float*)d_in[3];
    const int*   adj = (const int*)d_in[4];
    float* out = (float*)d_out;
    ushort* ws = (ushort*)d_ws;
    ushort* pacc = ws + PACC_OFF;
    float* pden = (float*)(ws + PDEN_USHORT_OFF);

    cvt_kernel<<<2816, 256, 0, stream>>>(x, wq, wk, wv, ws);
    qkv_kernel<<<dim3(24, 64), 256, 0, stream>>>(ws);
    attn_kernel<<<1024, 256, 0, stream>>>(adj, ws, pacc, pden);
    combine_kernel<<<2048, 256, 0, stream>>>(x, pacc, pden, out);
}

// Round 5
// 234.244 us; speedup vs baseline: 1.1405x; 1.1405x over previous
//
#include <hip/hip_runtime.h>
#include <hip/hip_bf16.h>

#define NN 4096
#define FF 512
#define NH 8
#define DH 64

typedef __attribute__((ext_vector_type(8))) short bf16x8;
typedef __attribute__((ext_vector_type(4))) float f32x4;

// ws layout in ushort elements:
//  X_BF  [4096][512]                    @ 0
//  W_BF  [3][512][512]                  @ 2097152   (Wq pre-scaled by 1/sqrt(512))
//  QF    [8][256 blk][2 half][64 ln][8] @ 2883584   (MFMA A-fragment order)
//  KF    [8][256 blk][2 half][64 ln][8] @ 4980736   (MFMA B-fragment order)
//  VF    [8][64 kb][4 dt][2 hf][64][8]  @ 7077888   (MFMA B-fragment order, d-major)
//  PACC  bf16 [2 ks][8 h][4096][64]     @ 9175040   (4194304 ushorts)
//  PDEN  f32  [2 ks][8 h][4096]         @ ushort 13369344
#define X_OFF  0
#define W_OFF  2097152
#define QF_OFF 2883584
#define KF_OFF 4980736
#define VF_OFF 7077888
#define PACC_OFF 9175040
#define PDEN_USHORT_OFF 13369344

__device__ __forceinline__ ushort f2bf(float f) {
    __hip_bfloat16 h = __float2bfloat16(f);
    return __builtin_bit_cast(ushort, h);
}
__device__ __forceinline__ float bf2f(ushort u) {
    unsigned int v = ((unsigned int)u) << 16;
    return __builtin_bit_cast(float, v);
}

// ---------------- kernel 0: f32 -> bf16 convert (x, Wq*scale, Wk, Wv) ----------------
__global__ __launch_bounds__(256) void cvt_kernel(const float* __restrict__ x,
                                                  const float* __restrict__ wq,
                                                  const float* __restrict__ wk,
                                                  const float* __restrict__ wv,
                                                  ushort* __restrict__ ws) {
    int i = blockIdx.x * 256 + threadIdx.x;
    int base = i * 4;
    const float* src;
    int off;
    float sc = 1.f;
    if (base < 2097152) { src = x; off = base; }
    else {
        int t = base - 2097152;
        int m = t >> 18;
        src = (m == 0) ? wq : ((m == 1) ? wk : wv);
        if (m == 0) sc = 0.044194173824159216f;   // 1/sqrt(512) folded into Wq
        off = t & 262143;
    }
    float4 v = *reinterpret_cast<const float4*>(src + off);
    ushort4 o;
    o.x = f2bf(v.x * sc); o.y = f2bf(v.y * sc); o.z = f2bf(v.z * sc); o.w = f2bf(v.w * sc);
    *reinterpret_cast<ushort4*>(ws + base) = o;
}

// ---------------- kernel 1: QKV projection, outputs in MFMA-fragment order ----------------
__global__ __launch_bounds__(256) void qkv_kernel(ushort* __restrict__ ws) {
    int bx = blockIdx.x;
    int mat = bx >> 3;          // 0=Q,1=K,2=V
    int fb  = bx & 7;           // head
    int mb  = blockIdx.y;
    int wave = threadIdx.x >> 6, lane = threadIdx.x & 63;
    int la = lane & 15, lk = lane >> 4;

    int m_base = mb * 64 + wave * 16;
    int f_base = fb * 64;

    const ushort* xb = ws + X_OFF;
    const ushort* wb = ws + W_OFF + mat * 262144;

    f32x4 acc[4];
#pragma unroll
    for (int t = 0; t < 4; ++t) acc[t] = (f32x4){0.f, 0.f, 0.f, 0.f};

#pragma unroll 4
    for (int k0 = 0; k0 < 512; k0 += 32) {
        bf16x8 a = *reinterpret_cast<const bf16x8*>(xb + (size_t)(m_base + la) * 512 + k0 + lk * 8);
#pragma unroll
        for (int ft = 0; ft < 4; ++ft) {
            bf16x8 b = *reinterpret_cast<const bf16x8*>(wb + (size_t)(f_base + ft * 16 + la) * 512 + k0 + lk * 8);
            acc[ft] = __builtin_amdgcn_mfma_f32_16x16x32_bf16(a, b, acc[ft], 0, 0, 0);
        }
    }

#pragma unroll
    for (int ft = 0; ft < 4; ++ft) {
#pragma unroll
        for (int r = 0; r < 4; ++r) {
            int n = m_base + lk * 4 + r;
            int d = ft * 16 + la;          // head-local feature
            ushort v = f2bf(acc[ft][r]);
            if (mat < 2) {
                ushort* base = ws + (mat == 0 ? QF_OFF : KF_OFF) + (size_t)fb * 262144;
                int blk = n >> 4, rr = n & 15;
                int half = d >> 5, lkk = (d >> 3) & 3, e = d & 7;
                base[(((size_t)blk * 2 + half) * 64 + lkk * 16 + rr) * 8 + e] = v;
            } else {
                ushort* base = ws + VF_OFF + (size_t)fb * 262144;
                int kb64 = n >> 6, kc = n & 63;
                int hf = kc >> 5, lkv = (kc >> 3) & 3, ev = kc & 7;
                int dt = d >> 4, lav = d & 15;
                base[((((size_t)kb64 * 4 + dt) * 2 + hf) * 64 + lkv * 16 + lav) * 8 + ev] = v;
            }
        }
    }
}

// ---------------- kernel 2: masked attention, phase-batched + adj prefetch ----------------
// grid 512: h = bid&7, qb = (bid>>3)&31, ks = bid>>8 (0..1). 4 waves x 32 q-rows, 2048 keys.
// Per 64-key body: issue K/V frag loads, then NEXT body's adj loads (kept in flight
// across the body boundary), then batched QK MFMA -> batched mask+exp -> P->LDS -> PV.

#define ATTN_BODY(ADJ_CUR, ADJ_NXT, KB, KBN)                                              \
    {                                                                                     \
        const int kb64_ = (KB);                                                           \
        bf16x8 kf[4][2], vb[4][2];                                                        \
        _Pragma("unroll")                                                                 \
        for (int kt = 0; kt < 4; ++kt) {                                                  \
            const ushort* kp = Kh + (((size_t)(kb64_ * 4 + kt) * 2) * 64 + lane) * 8;     \
            kf[kt][0] = *reinterpret_cast<const bf16x8*>(kp);                             \
            kf[kt][1] = *reinterpret_cast<const bf16x8*>(kp + 512);                       \
        }                                                                                 \
        _Pragma("unroll")                                                                 \
        for (int dt = 0; dt < 4; ++dt) {                                                  \
            const ushort* vp = Vh + ((((size_t)kb64_ * 4 + dt) * 2) * 64 + lane) * 8;     \
            vb[dt][0] = *reinterpret_cast<const bf16x8*>(vp);                             \
            vb[dt][1] = *reinterpret_cast<const bf16x8*>(vp + 512);                       \
        }                                                                                 \
        {   /* adj prefetch for next body — issued AFTER K/V so no wait drains it */      \
            int colb_ = (KBN) * 64 + la;                                                  \
            _Pragma("unroll")                                                             \
            for (int qs = 0; qs < 2; ++qs)                                                \
                _Pragma("unroll")                                                         \
                for (int r = 0; r < 4; ++r)                                               \
                    _Pragma("unroll")                                                     \
                    for (int kt = 0; kt < 4; ++kt)                                        \
                        ADJ_NXT[qs][r][kt] = __builtin_nontemporal_load(                  \
                            adjh + rowoff[qs][r] + colb_ + kt * 16);                      \
        }                                                                                 \
        f32x4 s[2][4];                                                                    \
        _Pragma("unroll")                                                                 \
        for (int kt = 0; kt < 4; ++kt)                                                    \
            _Pragma("unroll")                                                             \
            for (int qs = 0; qs < 2; ++qs) {                                              \
                s[qs][kt] = __builtin_amdgcn_mfma_f32_16x16x32_bf16(qa[qs][0], kf[kt][0], zero, 0, 0, 0); \
                s[qs][kt] = __builtin_amdgcn_mfma_f32_16x16x32_bf16(qa[qs][1], kf[kt][1], s[qs][kt], 0, 0, 0); \
            }                                                                             \
        _Pragma("unroll")                                                                 \
        for (int qs = 0; qs < 2; ++qs)                                                    \
            _Pragma("unroll")                                                             \
            for (int kt = 0; kt < 4; ++kt)                                                \
                _Pragma("unroll")                                                         \
                for (int r = 0; r < 4; ++r) {                                             \
                    float sv = ADJ_CUR[qs][r][kt] ? s[qs][kt][r] : -1e30f;                \
                    float e = __expf(sv);                                                 \
                    den[qs][r] += e;                                                      \
                    P[wave][qs * 16 + lk * 4 + r][kt * 16 + la] = f2bf(e);                \
                }                                                                         \
        _Pragma("unroll")                                                                 \
        for (int qs = 0; qs < 2; ++qs) {                                                  \
            bf16x8 pa0 = *reinterpret_cast<const bf16x8*>(&P[wave][qs * 16 + la][lk * 8]);      \
            bf16x8 pa1 = *reinterpret_cast<const bf16x8*>(&P[wave][qs * 16 + la][32 + lk * 8]); \
            _Pragma("unroll")                                                             \
            for (int dt = 0; dt < 4; ++dt) {                                              \
                acc[qs][dt] = __builtin_amdgcn_mfma_f32_16x16x32_bf16(pa0, vb[dt][0], acc[qs][dt], 0, 0, 0); \
                acc[qs][dt] = __builtin_amdgcn_mfma_f32_16x16x32_bf16(pa1, vb[dt][1], acc[qs][dt], 0, 0, 0); \
            }                                                                             \
        }                                                                                 \
    }

__global__ __launch_bounds__(256, 2) void attn_kernel(const int* __restrict__ adj,
                                                      const ushort* __restrict__ ws,
                                                      ushort* __restrict__ pacc,
                                                      float* __restrict__ pden) {
    __shared__ ushort P[4][32][72];

    int bid = blockIdx.x;
    int h = bid & 7, qb = (bid >> 3) & 31, ks = bid >> 8;
    int wave = threadIdx.x >> 6, lane = threadIdx.x & 63;
    int la = lane & 15, lk = lane >> 4;
    int q0 = qb * 128 + wave * 32;

    const ushort* Qh = ws + QF_OFF + (size_t)h * 262144;
    const ushort* Kh = ws + KF_OFF + (size_t)h * 262144;
    const ushort* Vh = ws + VF_OFF + (size_t)h * 262144;
    const int* adjh = adj + (size_t)h * 16777216;

    bf16x8 qa[2][2];
#pragma unroll
    for (int qs = 0; qs < 2; ++qs)
#pragma unroll
        for (int hf = 0; hf < 2; ++hf)
            qa[qs][hf] = *reinterpret_cast<const bf16x8*>(
                Qh + ((((size_t)((q0 >> 4) + qs)) * 2 + hf) * 64 + lane) * 8);

    f32x4 acc[2][4];
    float den[2][4];
    int rowoff[2][4];
#pragma unroll
    for (int qs = 0; qs < 2; ++qs)
#pragma unroll
        for (int r = 0; r < 4; ++r) {
            acc[qs][r] = (f32x4){0.f, 0.f, 0.f, 0.f};
            den[qs][r] = 0.f;
            rowoff[qs][r] = (q0 + qs * 16 + lk * 4 + r) * 4096;
        }

    const f32x4 zero = {0.f, 0.f, 0.f, 0.f};
    int kbase = ks * 32;

    int adjA[2][4][4], adjB[2][4][4];
    {   // prologue: adj for first body
        int colb_ = kbase * 64 + la;
#pragma unroll
        for (int qs = 0; qs < 2; ++qs)
#pragma unroll
            for (int r = 0; r < 4; ++r)
#pragma unroll
                for (int kt = 0; kt < 4; ++kt)
                    adjA[qs][r][kt] = __builtin_nontemporal_load(
                        adjh + rowoff[qs][r] + colb_ + kt * 16);
    }

    for (int it = 0; it < 32; it += 2) {
        int k0 = kbase + it;
        int k2n = (it + 2 < 32) ? (k0 + 2) : kbase;   // clamp last prefetch (unused, valid addr)
        ATTN_BODY(adjA, adjB, k0, k0 + 1)
        ATTN_BODY(adjB, adjA, k0 + 1, k2n)
    }

    // reduce den over the 16-lane key dimension
#pragma unroll
    for (int qs = 0; qs < 2; ++qs)
#pragma unroll
        for (int r = 0; r < 4; ++r)
#pragma unroll
            for (int m = 1; m < 16; m <<= 1)
                den[qs][r] += __shfl_xor(den[qs][r], m, 64);

    // store bf16 partial acc + f32 partial den
    ushort* pa_out = pacc + ((size_t)ks * 8 + h) * 4096 * 64;
#pragma unroll
    for (int qs = 0; qs < 2; ++qs)
#pragma unroll
        for (int dt = 0; dt < 4; ++dt)
#pragma unroll
            for (int r = 0; r < 4; ++r) {
                int q = q0 + qs * 16 + lk * 4 + r;
                __builtin_nontemporal_store(f2bf(acc[qs][dt][r]), pa_out + (size_t)q * 64 + dt * 16 + la);
            }
    if (la == 0) {
        float* pd = pden + ((size_t)ks * 8 + h) * 4096;
#pragma unroll
        for (int qs = 0; qs < 2; ++qs)
#pragma unroll
            for (int r = 0; r < 4; ++r)
                pd[q0 + qs * 16 + lk * 4 + r] = den[qs][r];
    }
}

// ---------------- kernel 3: combine bf16 partials + epilogue ----------------
__global__ __launch_bounds__(256) void combine_kernel(const float* __restrict__ x,
                                                      const ushort* __restrict__ pacc,
                                                      const float* __restrict__ pden,
                                                      float* __restrict__ out) {
    int idx = blockIdx.x * 256 + threadIdx.x;   // 524288 total
    int n = idx >> 7, fq = idx & 127;
    int h = fq >> 4;
    int d4 = (fq & 15) * 4;

    float4 o = make_float4(0.f, 0.f, 0.f, 0.f);
    float den = 0.f;
#pragma unroll
    for (int ksp = 0; ksp < 2; ++ksp) {
        const ushort* pa = pacc + (((size_t)ksp * 8 + h) * 4096 + n) * 64 + d4;
        ushort4 p = *reinterpret_cast<const ushort4*>(pa);
        o.x += bf2f(p.x); o.y += bf2f(p.y); o.z += bf2f(p.z); o.w += bf2f(p.w);
        den += pden[((size_t)ksp * 8 + h) * 4096 + n];
    }
    float4 xv = *reinterpret_cast<const float4*>(x + (size_t)n * 512 + fq * 4);
    float inv = 1.f / den;
    float4 r;
    r.x = o.x * inv + xv.x;
    r.y = o.y * inv + xv.y;
    r.z = o.z * inv + xv.z;
    r.w = o.w * inv + xv.w;
    r.x = (r.x > 0.f) ? r.x : (__expf(r.x) - 1.f);
    r.y = (r.y > 0.f) ? r.y : (__expf(r.y) - 1.f);
    r.z = (r.z > 0.f) ? r.z : (__expf(r.z) - 1.f);
    r.w = (r.w > 0.f) ? r.w : (__expf(r.w) - 1.f);
    *reinterpret_cast<float4*>(out + (size_t)n * 512 + fq * 4) = r;
}

extern "C" void kernel_launch(void* const* d_in, const int* in_sizes, int n_in,
                              void* d_out, int out_size, void* d_ws, size_t ws_size,
                              hipStream_t stream) {
    const float* x  = (const float*)d_in[0];
    const float* wq = (const float*)d_in[1];
    const float* wk = (const float*)d_in[2];
    const float* wv = (const float*)d_in[3];
    const int*   adj = (const int*)d_in[4];
    float* out = (float*)d_out;
    ushort* ws = (ushort*)d_ws;
    ushort* pacc = ws + PACC_OFF;
    float* pden = (float*)(ws + PDEN_USHORT_OFF);

    cvt_kernel<<<2816, 256, 0, stream>>>(x, wq, wk, wv, ws);
    qkv_kernel<<<dim3(24, 64), 256, 0, stream>>>(ws);
    attn_kernel<<<512, 256, 0, stream>>>(adj, ws, pacc, pden);
    combine_kernel<<<2048, 256, 0, stream>>>(x, pacc, pden, out);
}